// Round 1
// baseline (238.234 us; speedup 1.0000x reference)
//
#include <hip/hip_runtime.h>
#include <cstdint>
#include <cstddef>

// Linear attention: B=4 N=4096 C=768 H=12 d=64
// Pipeline: cast->bf16, GEMM1 (x@Wqkv^T, fused phi on q,k cols), kv/ksum
// partial reduction, reduce, y = z*(q.kv^T), GEMM2 (y@Wproj^T + bias).

typedef __attribute__((ext_vector_type(8))) short bf16x8;
typedef __attribute__((ext_vector_type(4))) float f32x4;

__device__ __forceinline__ unsigned short f2bf(float f) {
  uint32_t u = __builtin_bit_cast(uint32_t, f);
  u += 0x7FFFu + ((u >> 16) & 1u);  // RNE
  return (unsigned short)(u >> 16);
}
__device__ __forceinline__ float bf2f(unsigned short h) {
  uint32_t u = ((uint32_t)h) << 16;
  return __builtin_bit_cast(float, u);
}

__global__ __launch_bounds__(256) void cast_bf16_kernel(const float* __restrict__ in,
                                                        unsigned short* __restrict__ out,
                                                        int n4) {
  int i = blockIdx.x * 256 + threadIdx.x;
  if (i >= n4) return;
  float4 v = reinterpret_cast<const float4*>(in)[i];
  ushort4 o;
  o.x = f2bf(v.x); o.y = f2bf(v.y); o.z = f2bf(v.z); o.w = f2bf(v.w);
  reinterpret_cast<ushort4*>(out)[i] = o;
}

#define GLOAD_LDS16(g, s)                                                     \
  __builtin_amdgcn_global_load_lds(                                           \
      (const __attribute__((address_space(1))) void*)(g),                     \
      (__attribute__((address_space(3))) void*)(s), 16, 0, 0)

// C = A[M,K] * B[N,K]^T, bf16 in, fp32 accum. m97 structure: 128x128 tile,
// BK=32, 4 waves (2x2 of 64x64), 4x4 16x16x32 fragments per wave,
// global_load_lds width-16 staging (linear LDS), 2 barriers per K-step.
template <int PHI_COLS, bool OUT_BF16, bool BIAS>
__global__ __launch_bounds__(256) void gemm_bt_kernel(
    const unsigned short* __restrict__ A, const unsigned short* __restrict__ B,
    void* __restrict__ Cout, const float* __restrict__ bias, int M, int N, int K) {
  constexpr int BM = 128, BN = 128, BK = 32;
  __shared__ unsigned short As[BM * BK];
  __shared__ unsigned short Bs[BN * BK];
  const int t = threadIdx.x;
  const int l = t & 63;
  const int w = t >> 6;
  const int m0 = blockIdx.y * BM;
  const int n0 = blockIdx.x * BN;
  const int wm = (w >> 1) * 64;
  const int wn = (w & 1) * 64;
  const int r16 = l & 15;
  const int koff = (l >> 4) * 8;  // A/B frag: 8 contiguous K per lane

  f32x4 acc[4][4] = {};

  // staging: thread t covers 16B chunk t; rows t>>2, k-chunk (t&3)*8
  const int srow = t >> 2;
  const int skc = (t & 3) * 8;
  const unsigned short* gA0 = A + (size_t)(m0 + srow) * K + skc;
  const unsigned short* gA1 = A + (size_t)(m0 + 64 + srow) * K + skc;
  const unsigned short* gB0 = B + (size_t)(n0 + srow) * K + skc;
  const unsigned short* gB1 = B + (size_t)(n0 + 64 + srow) * K + skc;
  // wave-uniform LDS bases (HW adds lane*16)
  unsigned short* lA0 = &As[w * 512];
  unsigned short* lA1 = &As[64 * BK + w * 512];
  unsigned short* lB0 = &Bs[w * 512];
  unsigned short* lB1 = &Bs[64 * BK + w * 512];

  for (int k0 = 0; k0 < K; k0 += BK) {
    GLOAD_LDS16(gA0 + k0, lA0);
    GLOAD_LDS16(gA1 + k0, lA1);
    GLOAD_LDS16(gB0 + k0, lB0);
    GLOAD_LDS16(gB1 + k0, lB1);
    __syncthreads();  // compiler drains vmcnt before barrier

    bf16x8 af[4], bfr[4];
#pragma unroll
    for (int mi = 0; mi < 4; ++mi)
      af[mi] = *reinterpret_cast<const bf16x8*>(&As[(wm + mi * 16 + r16) * BK + koff]);
#pragma unroll
    for (int ni = 0; ni < 4; ++ni)
      bfr[ni] = *reinterpret_cast<const bf16x8*>(&Bs[(wn + ni * 16 + r16) * BK + koff]);
#pragma unroll
    for (int mi = 0; mi < 4; ++mi)
#pragma unroll
      for (int ni = 0; ni < 4; ++ni)
        acc[mi][ni] = __builtin_amdgcn_mfma_f32_16x16x32_bf16(af[mi], bfr[ni], acc[mi][ni], 0, 0, 0);
    __syncthreads();
  }

  // epilogue: C/D layout col=lane&15, row=(lane>>4)*4+reg (m89/m91 verified)
  const int rbase = (l >> 4) * 4;
#pragma unroll
  for (int mi = 0; mi < 4; ++mi) {
    const int row = m0 + wm + mi * 16 + rbase;
#pragma unroll
    for (int ni = 0; ni < 4; ++ni) {
      const int col = n0 + wn + ni * 16 + r16;
      f32x4 v = acc[mi][ni];
      float bv = 0.0f;
      if constexpr (BIAS) bv = bias[col];
#pragma unroll
      for (int r = 0; r < 4; ++r) {
        float x = v[r] + bv;
        if constexpr (PHI_COLS > 0) {
          if (col < PHI_COLS) x = (x > 0.0f) ? (x + 1.0f) : __expf(x);  // elu+1
        }
        if constexpr (OUT_BF16)
          ((unsigned short*)Cout)[(size_t)(row + r) * N + col] = f2bf(x);
        else
          ((float*)Cout)[(size_t)(row + r) * N + col] = x;
      }
    }
  }
}

// kv[m,d] = sum_n k[n,d]*v[n,m]; ksum[d] = sum_n k[n,d].  Partial over 512-n
// chunks, 8 chunks per (b,h).  Thread owns a 4x4 (m,d) tile.
__global__ __launch_bounds__(256) void kv_partial_kernel(
    const unsigned short* __restrict__ qkv, float* __restrict__ kv_part,
    float* __restrict__ ksum_part) {
  const int bh = blockIdx.x;   // 48
  const int chunk = blockIdx.y;  // 8
  const int b = bh / 12, h = bh % 12;
  const int t = threadIdx.x;
  const int tm = (t >> 4) * 4;
  const int td = (t & 15) * 4;
  const unsigned short* base = qkv + ((size_t)(b * 4096 + chunk * 512)) * 2304;
  const unsigned short* kptr = base + 768 + h * 64 + td;
  const unsigned short* vptr = base + 1536 + h * 64 + tm;
  float acc[4][4] = {};
  float ks[4] = {};
#pragma unroll 4
  for (int n = 0; n < 512; ++n) {
    const size_t off = (size_t)n * 2304;
    ushort4 ku = *reinterpret_cast<const ushort4*>(kptr + off);
    ushort4 vu = *reinterpret_cast<const ushort4*>(vptr + off);
    float kf[4] = {bf2f(ku.x), bf2f(ku.y), bf2f(ku.z), bf2f(ku.w)};
    float vf[4] = {bf2f(vu.x), bf2f(vu.y), bf2f(vu.z), bf2f(vu.w)};
#pragma unroll
    for (int i = 0; i < 4; ++i)
#pragma unroll
      for (int j = 0; j < 4; ++j) acc[i][j] += vf[i] * kf[j];
#pragma unroll
    for (int j = 0; j < 4; ++j) ks[j] += kf[j];
  }
  float* kvp = kv_part + ((size_t)(bh * 8 + chunk)) * 4096;
#pragma unroll
  for (int i = 0; i < 4; ++i)
#pragma unroll
    for (int j = 0; j < 4; ++j) kvp[(tm + i) * 64 + td + j] = acc[i][j];
  if (tm == 0) {
    float* ksp = ksum_part + (size_t)(bh * 8 + chunk) * 64;
#pragma unroll
    for (int j = 0; j < 4; ++j) ksp[td + j] = ks[j];
  }
}

__global__ __launch_bounds__(256) void kv_reduce_kernel(
    const float* __restrict__ kv_part, const float* __restrict__ ksum_part,
    float* __restrict__ kv, float* __restrict__ ksum) {
  const int bh = blockIdx.x;
  const int t = threadIdx.x;
  for (int e = t; e < 4096; e += 256) {
    float s = 0.f;
#pragma unroll
    for (int c = 0; c < 8; ++c) s += kv_part[((size_t)(bh * 8 + c)) * 4096 + e];
    kv[(size_t)bh * 4096 + e] = s;
  }
  if (t < 64) {
    float s = 0.f;
#pragma unroll
    for (int c = 0; c < 8; ++c) s += ksum_part[(size_t)(bh * 8 + c) * 64 + t];
    ksum[bh * 64 + t] = s;
  }
}

// y[n,m] = z[n] * sum_d q[n,d] kv[m,d];  z[n] = 1/(q[n,:].ksum + eps)
// Block: one (b,h) x 64-row chunk; LDS-transposed q and kv for float4 reads.
__global__ __launch_bounds__(256) void y_kernel(
    const unsigned short* __restrict__ qkv, const float* __restrict__ kv,
    const float* __restrict__ ksum, unsigned short* __restrict__ ybf) {
  const int bh = blockIdx.x;  // 48
  const int nc = blockIdx.y;  // 64
  const int b = bh / 12, h = bh % 12;
  const int t = threadIdx.x;
  __shared__ float qs[64][64];   // [d][n]
  __shared__ float kvs[64][64];  // [d][m]
  __shared__ float zs[64];
  const int n0 = nc * 64;
  const unsigned short* qbase = qkv + ((size_t)(b * 4096 + n0)) * 2304 + h * 64;
  {
    const int nl = t & 63, dc = t >> 6;
    const unsigned short* qrow = qbase + (size_t)nl * 2304;
    const float* kvrow = kv + (size_t)bh * 4096 + (size_t)nl * 64;
#pragma unroll
    for (int dd = 0; dd < 4; ++dd) {
      const int d0 = dc * 16 + dd * 4;
      ushort4 qu = *reinterpret_cast<const ushort4*>(qrow + d0);
      qs[d0 + 0][nl] = bf2f(qu.x);
      qs[d0 + 1][nl] = bf2f(qu.y);
      qs[d0 + 2][nl] = bf2f(qu.z);
      qs[d0 + 3][nl] = bf2f(qu.w);
      float4 kf = *reinterpret_cast<const float4*>(kvrow + d0);
      kvs[d0 + 0][nl] = kf.x;
      kvs[d0 + 1][nl] = kf.y;
      kvs[d0 + 2][nl] = kf.z;
      kvs[d0 + 3][nl] = kf.w;
    }
  }
  __syncthreads();
  if (t < 64) {
    const float* ksp = ksum + bh * 64;
    float s = 0.f;
#pragma unroll
    for (int d = 0; d < 64; ++d) s += qs[d][t] * ksp[d];
    zs[t] = 1.0f / (s + 1e-6f);
  }
  __syncthreads();
  const int tn = (t >> 4) * 4;
  const int tmm = (t & 15) * 4;
  float acc[4][4] = {};
#pragma unroll 4
  for (int d = 0; d < 64; ++d) {
    float4 qv = *reinterpret_cast<const float4*>(&qs[d][tn]);
    float4 kf = *reinterpret_cast<const float4*>(&kvs[d][tmm]);
    const float qa[4] = {qv.x, qv.y, qv.z, qv.w};
    const float ka[4] = {kf.x, kf.y, kf.z, kf.w};
#pragma unroll
    for (int i = 0; i < 4; ++i)
#pragma unroll
      for (int j = 0; j < 4; ++j) acc[i][j] += qa[i] * ka[j];
  }
  unsigned short* yrow = ybf + ((size_t)(b * 4096 + n0)) * 768 + h * 64;
#pragma unroll
  for (int i = 0; i < 4; ++i) {
    const int n = tn + i;
    const float z = zs[n];
    ushort4 o;
    o.x = f2bf(acc[i][0] * z);
    o.y = f2bf(acc[i][1] * z);
    o.z = f2bf(acc[i][2] * z);
    o.w = f2bf(acc[i][3] * z);
    *reinterpret_cast<ushort4*>(yrow + (size_t)n * 768 + tmm) = o;
  }
}

extern "C" void kernel_launch(void* const* d_in, const int* in_sizes, int n_in,
                              void* d_out, int out_size, void* d_ws, size_t ws_size,
                              hipStream_t stream) {
  const float* x = (const float*)d_in[0];
  const float* Wqkv = (const float*)d_in[1];
  const float* Wproj = (const float*)d_in[2];
  const float* bproj = (const float*)d_in[3];
  float* out = (float*)d_out;

  const int M = 16384;   // B*N tokens
  const int C = 768;
  const int N1 = 2304;   // 3C

  char* ws = (char*)d_ws;
  size_t off = 0;
  unsigned short* xb = (unsigned short*)(ws + off);  off += (size_t)M * C * 2;      // 25.2MB
  unsigned short* wqb = (unsigned short*)(ws + off); off += (size_t)N1 * C * 2;     // 3.5MB
  unsigned short* wpb = (unsigned short*)(ws + off); off += (size_t)C * C * 2;      // 1.2MB
  unsigned short* qkvb = (unsigned short*)(ws + off); off += (size_t)M * N1 * 2;    // 75.5MB
  float* kv_part = (float*)(ws + off);   off += (size_t)48 * 8 * 4096 * 4;          // 6.3MB
  float* ksum_part = (float*)(ws + off); off += (size_t)48 * 8 * 64 * 4;            // 96KB
  float* kv = (float*)(ws + off);        off += (size_t)48 * 4096 * 4;              // 768KB
  float* ksum = (float*)(ws + off);      off += (size_t)48 * 64 * 4;                // 12KB
  unsigned short* yb = (unsigned short*)(ws + off); off += (size_t)M * C * 2;       // 25.2MB

  cast_bf16_kernel<<<(M * C / 4 + 255) / 256, 256, 0, stream>>>(x, xb, M * C / 4);
  cast_bf16_kernel<<<(N1 * C / 4 + 255) / 256, 256, 0, stream>>>(Wqkv, wqb, N1 * C / 4);
  cast_bf16_kernel<<<(C * C / 4 + 255) / 256, 256, 0, stream>>>(Wproj, wpb, C * C / 4);

  // qkv = x @ Wqkv^T, phi fused on q,k columns (col < 1536), bf16 out
  gemm_bt_kernel<1536, true, false>
      <<<dim3(N1 / 128, M / 128), 256, 0, stream>>>(xb, wqb, qkvb, nullptr, M, N1, C);

  kv_partial_kernel<<<dim3(48, 8), 256, 0, stream>>>(qkvb, kv_part, ksum_part);
  kv_reduce_kernel<<<48, 256, 0, stream>>>(kv_part, ksum_part, kv, ksum);
  y_kernel<<<dim3(48, 64), 256, 0, stream>>>(qkvb, kv, ksum, yb);

  // out = y @ Wproj^T + b, fp32 out
  gemm_bt_kernel<0, false, true>
      <<<dim3(C / 128, M / 128), 256, 0, stream>>>(yb, wpb, out, bproj, M, C, C);
}

// Round 2
// 229.354 us; speedup vs baseline: 1.0387x; 1.0387x over previous
//
#include <hip/hip_runtime.h>
#include <cstdint>
#include <cstddef>

// Linear attention: B=4 N=4096 C=768 H=12 d=64
// Pipeline: cast->bf16, GEMM1 256x256 8-phase (x@Wqkv^T, fused phi), kv/ksum
// partial reduction, reduce, y = z*(q.kv^T), GEMM2 (y@Wproj^T + bias).

typedef __attribute__((ext_vector_type(8))) short bf16x8;
typedef __attribute__((ext_vector_type(4))) float f32x4;

__device__ __forceinline__ unsigned short f2bf(float f) {
  uint32_t u = __builtin_bit_cast(uint32_t, f);
  u += 0x7FFFu + ((u >> 16) & 1u);  // RNE
  return (unsigned short)(u >> 16);
}
__device__ __forceinline__ float bf2f(unsigned short h) {
  uint32_t u = ((uint32_t)h) << 16;
  return __builtin_bit_cast(float, u);
}

__global__ __launch_bounds__(256) void cast_bf16_kernel(const float* __restrict__ in,
                                                        unsigned short* __restrict__ out,
                                                        int n4) {
  int i = blockIdx.x * 256 + threadIdx.x;
  if (i >= n4) return;
  float4 v = reinterpret_cast<const float4*>(in)[i];
  ushort4 o;
  o.x = f2bf(v.x); o.y = f2bf(v.y); o.z = f2bf(v.z); o.w = f2bf(v.w);
  reinterpret_cast<ushort4*>(out)[i] = o;
}

#define GLOAD_LDS16(g, s)                                                     \
  __builtin_amdgcn_global_load_lds(                                           \
      (const __attribute__((address_space(1))) void*)(g),                     \
      (__attribute__((address_space(3))) void*)(s), 16, 0, 0)

// ============================================================================
// 256x256 tile, 8 waves (2M x 4N), BK=32 sub-tiles, 4-slot LDS ring (128KiB),
// 2 phases per sub-tile (16 MFMA each), counted vmcnt (8/4/0), XOR swizzle on
// both staging source and ds_read (rule #21), setprio around MFMA (T5),
// bijective XCD block swizzle (T1/m204).
//
// Race-freedom: tile t's phases stage tile t+3 into slot (t+3)&3 == (t-1)&3.
// Tile t-1's LDS reads all completed before tile t-1's final barrier (each
// wave waits lgkmcnt(0) before its MFMAs), so the slot is dead. vmcnt(8) at
// tile t's end allows tiles t+2,t+3 (8 newest load-instrs) in flight while
// guaranteeing tile t+1 (>=9th newest) has landed; barrier after makes all
// waves' staging visible.
// ============================================================================
template <int PHI_COLS, bool OUT_BF16, bool BIAS>
__global__ __launch_bounds__(512, 2) void gemm256_8p(
    const unsigned short* __restrict__ A, const unsigned short* __restrict__ B,
    void* __restrict__ Cout, const float* __restrict__ bias, int M, int N, int K) {
  // LDS: A slots [4][256*32] at 0, B slots at +32768 (ushort units). 128 KiB.
  __shared__ unsigned short smem[65536];
  const int t = threadIdx.x;
  const int w = t >> 6;
  const int l = t & 63;
  const int r16 = l & 15;
  const int c4 = l >> 4;

  // bijective XCD swizzle over linear block id (m204)
  const int nx = gridDim.x;
  const int nwg = gridDim.x * gridDim.y;
  int lin = blockIdx.y * nx + blockIdx.x;
  {
    const int q = nwg >> 3, r = nwg & 7;
    const int xcd = lin & 7, idx = lin >> 3;
    lin = (xcd < r ? xcd * (q + 1) : r * (q + 1) + (xcd - r) * q) + idx;
  }
  const int m0 = (lin / nx) << 8;
  const int n0 = (lin % nx) << 8;

  // staging: thread t covers 16B chunk (row = i*128 + t>>2, slot chunk t&3),
  // global chunk pre-swizzled: c_g = (t&3) ^ ((row>>1)&3) = (t&3) ^ ((t>>3)&3)
  const int srow = t >> 2;
  const int scg = (t & 3) ^ ((t >> 3) & 3);
  const unsigned short* gA0 = A + (size_t)(m0 + srow) * K + scg * 8;
  const unsigned short* gA1 = A + (size_t)(m0 + 128 + srow) * K + scg * 8;
  const unsigned short* gB0 = B + (size_t)(n0 + srow) * K + scg * 8;
  const unsigned short* gB1 = B + (size_t)(n0 + 128 + srow) * K + scg * 8;

#define STAGE_A(tt_)                                                          \
  {                                                                           \
    const int s_ = ((tt_) & 3) * 8192 + w * 512;                              \
    GLOAD_LDS16(gA0 + (tt_) * 32, &smem[s_]);                                 \
    GLOAD_LDS16(gA1 + (tt_) * 32, &smem[s_ + 4096]);                          \
  }
#define STAGE_B(tt_)                                                          \
  {                                                                           \
    const int s_ = 32768 + ((tt_) & 3) * 8192 + w * 512;                      \
    GLOAD_LDS16(gB0 + (tt_) * 32, &smem[s_]);                                 \
    GLOAD_LDS16(gB1 + (tt_) * 32, &smem[s_ + 4096]);                          \
  }

  // fragment read offsets (ushort units), read-side XOR swizzle matches staging
  const int swzc = (c4 ^ ((r16 >> 1) & 3)) * 8;
  const int aoff = ((w >> 2) * 128 + r16) * 32 + swzc;
  const int boff = 32768 + ((w & 3) * 64 + r16) * 32 + swzc;

  f32x4 acc[8][4] = {};
  const int NT = K >> 5;  // BK=32 sub-tiles; K=768 -> 24

  // prologue: stage tiles 0,1,2 (12 load-instrs); wait tile 0 (keep 8 in flight)
  STAGE_A(0) STAGE_B(0) STAGE_A(1) STAGE_B(1) STAGE_A(2) STAGE_B(2)
  asm volatile("s_waitcnt vmcnt(8)" ::: "memory");
  __builtin_amdgcn_s_barrier();

  for (int tt = 0; tt < NT; ++tt) {
    const unsigned short* pA = &smem[(tt & 3) * 8192 + aoff];
    const unsigned short* pB = &smem[(tt & 3) * 8192 + boff];

    // ---- phase 0: read A mi0-3 + all B, stage next A, MFMA quadrant 0 ----
    bf16x8 af[4], ag[4], bq[4];
#pragma unroll
    for (int i = 0; i < 4; ++i) af[i] = *reinterpret_cast<const bf16x8*>(pA + i * 512);
#pragma unroll
    for (int i = 0; i < 4; ++i) bq[i] = *reinterpret_cast<const bf16x8*>(pB + i * 512);
    if (tt + 3 < NT) STAGE_A(tt + 3);
    __builtin_amdgcn_s_barrier();
    asm volatile("s_waitcnt lgkmcnt(0)" ::: "memory");
    __builtin_amdgcn_sched_barrier(0);
    __builtin_amdgcn_s_setprio(1);
#pragma unroll
    for (int mi = 0; mi < 4; ++mi)
#pragma unroll
      for (int ni = 0; ni < 4; ++ni)
        acc[mi][ni] = __builtin_amdgcn_mfma_f32_16x16x32_bf16(af[mi], bq[ni], acc[mi][ni], 0, 0, 0);
    __builtin_amdgcn_s_setprio(0);
    __builtin_amdgcn_s_barrier();

    // ---- phase 1: read A mi4-7, stage next B, MFMA quadrant 1 ----
#pragma unroll
    for (int i = 0; i < 4; ++i) ag[i] = *reinterpret_cast<const bf16x8*>(pA + (4 + i) * 512);
    if (tt + 3 < NT) STAGE_B(tt + 3);
    __builtin_amdgcn_s_barrier();
    asm volatile("s_waitcnt lgkmcnt(0)" ::: "memory");
    __builtin_amdgcn_sched_barrier(0);
    __builtin_amdgcn_s_setprio(1);
#pragma unroll
    for (int mi = 0; mi < 4; ++mi)
#pragma unroll
      for (int ni = 0; ni < 4; ++ni)
        acc[4 + mi][ni] = __builtin_amdgcn_mfma_f32_16x16x32_bf16(ag[mi], bq[ni], acc[4 + mi][ni], 0, 0, 0);
    __builtin_amdgcn_s_setprio(0);
    // counted vmcnt at tile end: tiles tt+2, tt+3 may stay in flight
    if (tt < NT - 3) {
      asm volatile("s_waitcnt vmcnt(8)" ::: "memory");
    } else if (tt == NT - 3) {
      asm volatile("s_waitcnt vmcnt(4)" ::: "memory");
    } else if (tt == NT - 2) {
      asm volatile("s_waitcnt vmcnt(0)" ::: "memory");
    }
    __builtin_amdgcn_s_barrier();
  }

  // epilogue: C/D layout col=lane&15, row=(lane>>4)*4+reg (m89/m91 verified)
  const int orow0 = m0 + (w >> 2) * 128 + c4 * 4;
  const int ocol0 = n0 + (w & 3) * 64 + r16;
#pragma unroll
  for (int mi = 0; mi < 8; ++mi) {
#pragma unroll
    for (int ni = 0; ni < 4; ++ni) {
      const int col = ocol0 + ni * 16;
      float bv = 0.0f;
      if constexpr (BIAS) bv = bias[col];
      f32x4 v = acc[mi][ni];
#pragma unroll
      for (int r = 0; r < 4; ++r) {
        const int row = orow0 + mi * 16 + r;
        float x = v[r] + bv;
        if constexpr (PHI_COLS > 0) {
          if (col < PHI_COLS) x = (x > 0.0f) ? (x + 1.0f) : __expf(x);  // elu+1
        }
        if constexpr (OUT_BF16)
          ((unsigned short*)Cout)[(size_t)row * N + col] = f2bf(x);
        else
          ((float*)Cout)[(size_t)row * N + col] = x;
      }
    }
  }
#undef STAGE_A
#undef STAGE_B
}

// kv[m,d] = sum_n k[n,d]*v[n,m]; ksum[d] = sum_n k[n,d].  Partial over 512-n
// chunks, 8 chunks per (b,h).  Thread owns a 4x4 (m,d) tile.
__global__ __launch_bounds__(256) void kv_partial_kernel(
    const unsigned short* __restrict__ qkv, float* __restrict__ kv_part,
    float* __restrict__ ksum_part) {
  const int bh = blockIdx.x;   // 48
  const int chunk = blockIdx.y;  // 8
  const int b = bh / 12, h = bh % 12;
  const int t = threadIdx.x;
  const int tm = (t >> 4) * 4;
  const int td = (t & 15) * 4;
  const unsigned short* base = qkv + ((size_t)(b * 4096 + chunk * 512)) * 2304;
  const unsigned short* kptr = base + 768 + h * 64 + td;
  const unsigned short* vptr = base + 1536 + h * 64 + tm;
  float acc[4][4] = {};
  float ks[4] = {};
#pragma unroll 4
  for (int n = 0; n < 512; ++n) {
    const size_t off = (size_t)n * 2304;
    ushort4 ku = *reinterpret_cast<const ushort4*>(kptr + off);
    ushort4 vu = *reinterpret_cast<const ushort4*>(vptr + off);
    float kf[4] = {bf2f(ku.x), bf2f(ku.y), bf2f(ku.z), bf2f(ku.w)};
    float vf[4] = {bf2f(vu.x), bf2f(vu.y), bf2f(vu.z), bf2f(vu.w)};
#pragma unroll
    for (int i = 0; i < 4; ++i)
#pragma unroll
      for (int j = 0; j < 4; ++j) acc[i][j] += vf[i] * kf[j];
#pragma unroll
    for (int j = 0; j < 4; ++j) ks[j] += kf[j];
  }
  float* kvp = kv_part + ((size_t)(bh * 8 + chunk)) * 4096;
#pragma unroll
  for (int i = 0; i < 4; ++i)
#pragma unroll
    for (int j = 0; j < 4; ++j) kvp[(tm + i) * 64 + td + j] = acc[i][j];
  if (tm == 0) {
    float* ksp = ksum_part + (size_t)(bh * 8 + chunk) * 64;
#pragma unroll
    for (int j = 0; j < 4; ++j) ksp[td + j] = ks[j];
  }
}

__global__ __launch_bounds__(256) void kv_reduce_kernel(
    const float* __restrict__ kv_part, const float* __restrict__ ksum_part,
    float* __restrict__ kv, float* __restrict__ ksum) {
  const int bh = blockIdx.x;
  const int t = threadIdx.x;
  for (int e = t; e < 4096; e += 256) {
    float s = 0.f;
#pragma unroll
    for (int c = 0; c < 8; ++c) s += kv_part[((size_t)(bh * 8 + c)) * 4096 + e];
    kv[(size_t)bh * 4096 + e] = s;
  }
  if (t < 64) {
    float s = 0.f;
#pragma unroll
    for (int c = 0; c < 8; ++c) s += ksum_part[(size_t)(bh * 8 + c) * 64 + t];
    ksum[bh * 64 + t] = s;
  }
}

// y[n,m] = z[n] * sum_d q[n,d] kv[m,d];  z[n] = 1/(q[n,:].ksum + eps)
__global__ __launch_bounds__(256) void y_kernel(
    const unsigned short* __restrict__ qkv, const float* __restrict__ kv,
    const float* __restrict__ ksum, unsigned short* __restrict__ ybf) {
  const int bh = blockIdx.x;  // 48
  const int nc = blockIdx.y;  // 64
  const int b = bh / 12, h = bh % 12;
  const int t = threadIdx.x;
  __shared__ float qs[64][64];   // [d][n]
  __shared__ float kvs[64][64];  // [d][m]
  __shared__ float zs[64];
  const int n0 = nc * 64;
  const unsigned short* qbase = qkv + ((size_t)(b * 4096 + n0)) * 2304 + h * 64;
  {
    const int nl = t & 63, dc = t >> 6;
    const unsigned short* qrow = qbase + (size_t)nl * 2304;
    const float* kvrow = kv + (size_t)bh * 4096 + (size_t)nl * 64;
#pragma unroll
    for (int dd = 0; dd < 4; ++dd) {
      const int d0 = dc * 16 + dd * 4;
      ushort4 qu = *reinterpret_cast<const ushort4*>(qrow + d0);
      qs[d0 + 0][nl] = bf2f(qu.x);
      qs[d0 + 1][nl] = bf2f(qu.y);
      qs[d0 + 2][nl] = bf2f(qu.z);
      qs[d0 + 3][nl] = bf2f(qu.w);
      float4 kf = *reinterpret_cast<const float4*>(kvrow + d0);
      kvs[d0 + 0][nl] = kf.x;
      kvs[d0 + 1][nl] = kf.y;
      kvs[d0 + 2][nl] = kf.z;
      kvs[d0 + 3][nl] = kf.w;
    }
  }
  __syncthreads();
  if (t < 64) {
    const float* ksp = ksum + bh * 64;
    float s = 0.f;
#pragma unroll
    for (int d = 0; d < 64; ++d) s += qs[d][t] * ksp[d];
    zs[t] = 1.0f / (s + 1e-6f);
  }
  __syncthreads();
  const int tn = (t >> 4) * 4;
  const int tmm = (t & 15) * 4;
  float acc[4][4] = {};
#pragma unroll 4
  for (int d = 0; d < 64; ++d) {
    float4 qv = *reinterpret_cast<const float4*>(&qs[d][tn]);
    float4 kf = *reinterpret_cast<const float4*>(&kvs[d][tmm]);
    const float qa[4] = {qv.x, qv.y, qv.z, qv.w};
    const float ka[4] = {kf.x, kf.y, kf.z, kf.w};
#pragma unroll
    for (int i = 0; i < 4; ++i)
#pragma unroll
      for (int j = 0; j < 4; ++j) acc[i][j] += qa[i] * ka[j];
  }
  unsigned short* yrow = ybf + ((size_t)(b * 4096 + n0)) * 768 + h * 64;
#pragma unroll
  for (int i = 0; i < 4; ++i) {
    const int n = tn + i;
    const float z = zs[n];
    ushort4 o;
    o.x = f2bf(acc[i][0] * z);
    o.y = f2bf(acc[i][1] * z);
    o.z = f2bf(acc[i][2] * z);
    o.w = f2bf(acc[i][3] * z);
    *reinterpret_cast<ushort4*>(yrow + (size_t)n * 768 + tmm) = o;
  }
}

extern "C" void kernel_launch(void* const* d_in, const int* in_sizes, int n_in,
                              void* d_out, int out_size, void* d_ws, size_t ws_size,
                              hipStream_t stream) {
  const float* x = (const float*)d_in[0];
  const float* Wqkv = (const float*)d_in[1];
  const float* Wproj = (const float*)d_in[2];
  const float* bproj = (const float*)d_in[3];
  float* out = (float*)d_out;

  const int M = 16384;   // B*N tokens
  const int C = 768;
  const int N1 = 2304;   // 3C

  char* ws = (char*)d_ws;
  size_t off = 0;
  unsigned short* xb = (unsigned short*)(ws + off);  off += (size_t)M * C * 2;
  unsigned short* wqb = (unsigned short*)(ws + off); off += (size_t)N1 * C * 2;
  unsigned short* wpb = (unsigned short*)(ws + off); off += (size_t)C * C * 2;
  unsigned short* qkvb = (unsigned short*)(ws + off); off += (size_t)M * N1 * 2;
  float* kv_part = (float*)(ws + off);   off += (size_t)48 * 8 * 4096 * 4;
  float* ksum_part = (float*)(ws + off); off += (size_t)48 * 8 * 64 * 4;
  float* kv = (float*)(ws + off);        off += (size_t)48 * 4096 * 4;
  float* ksum = (float*)(ws + off);      off += (size_t)48 * 64 * 4;
  unsigned short* yb = (unsigned short*)(ws + off); off += (size_t)M * C * 2;

  cast_bf16_kernel<<<(M * C / 4 + 255) / 256, 256, 0, stream>>>(x, xb, M * C / 4);
  cast_bf16_kernel<<<(N1 * C / 4 + 255) / 256, 256, 0, stream>>>(Wqkv, wqb, N1 * C / 4);
  cast_bf16_kernel<<<(C * C / 4 + 255) / 256, 256, 0, stream>>>(Wproj, wpb, C * C / 4);

  // qkv = x @ Wqkv^T, phi fused on q,k columns (col < 1536), bf16 out
  gemm256_8p<1536, true, false>
      <<<dim3(N1 / 256, M / 256), 512, 0, stream>>>(xb, wqb, qkvb, nullptr, M, N1, C);

  kv_partial_kernel<<<dim3(48, 8), 256, 0, stream>>>(qkvb, kv_part, ksum_part);
  kv_reduce_kernel<<<48, 256, 0, stream>>>(kv_part, ksum_part, kv, ksum);
  y_kernel<<<dim3(48, 64), 256, 0, stream>>>(qkvb, kv, ksum, yb);

  // out = y @ Wproj^T + b, fp32 out
  gemm256_8p<0, false, true>
      <<<dim3(C / 256, M / 256), 512, 0, stream>>>(yb, wpb, out, bproj, M, C, C);
}

// Round 3
// 223.207 us; speedup vs baseline: 1.0673x; 1.0275x over previous
//
#include <hip/hip_runtime.h>
#include <cstdint>
#include <cstddef>

// Linear attention: B=4 N=4096 C=768 H=12 d=64
// Pipeline: cast->bf16, GEMM1 256x256 ring (x@Wqkv^T, fused phi), kv/ksum
// partial reduction, reduce, y = z*(q.kv^T), GEMM2 (y@Wproj^T + bias).

typedef __attribute__((ext_vector_type(8))) short bf16x8;
typedef __attribute__((ext_vector_type(4))) float f32x4;

__device__ __forceinline__ unsigned short f2bf(float f) {
  uint32_t u = __builtin_bit_cast(uint32_t, f);
  u += 0x7FFFu + ((u >> 16) & 1u);  // RNE
  return (unsigned short)(u >> 16);
}
__device__ __forceinline__ float bf2f(unsigned short h) {
  uint32_t u = ((uint32_t)h) << 16;
  return __builtin_bit_cast(float, u);
}

__global__ __launch_bounds__(256) void cast_bf16_kernel(const float* __restrict__ in,
                                                        unsigned short* __restrict__ out,
                                                        int n4) {
  int i = blockIdx.x * 256 + threadIdx.x;
  if (i >= n4) return;
  float4 v = reinterpret_cast<const float4*>(in)[i];
  ushort4 o;
  o.x = f2bf(v.x); o.y = f2bf(v.y); o.z = f2bf(v.z); o.w = f2bf(v.w);
  reinterpret_cast<ushort4*>(out)[i] = o;
}

#define GLOAD_LDS16(g, s)                                                     \
  __builtin_amdgcn_global_load_lds(                                           \
      (const __attribute__((address_space(1))) void*)(g),                     \
      (__attribute__((address_space(3))) void*)(s), 16, 0, 0)

// ============================================================================
// 256x256 tile, 8 waves (2M x 4N), BK=32 sub-tiles, 4-slot LDS ring (128KiB).
// ONE scheduling region per sub-tile: {STAGE x4, 12 ds_read, 32 MFMA} with the
// compiler free to interleave (fine-grained lgkmcnt), then a single
// lgkmcnt(0) + counted vmcnt(8) + s_barrier per sub-tile.
//
// Race-freedom: tile t stages tile t+3 into slot (t+3)&3 == (t-1)&3. All
// waves' ds_reads of slot (t-1)&3 completed before tile t-1's end barrier
// (enforced by the explicit lgkmcnt(0) before that barrier), so the slot is
// dead when staging lands. vmcnt(8) at tile t's end leaves tiles t+2,t+3
// (8 newest load-instrs per wave) in flight while guaranteeing tile t+1
// landed; the barrier makes all waves' staging mutually visible. The empty
// asm "memory" fence after the barrier pins next-tile ds_reads below it.
// ============================================================================
template <int PHI_COLS, bool OUT_BF16, bool BIAS>
__global__ __launch_bounds__(512, 2) void gemm256_ring(
    const unsigned short* __restrict__ A, const unsigned short* __restrict__ B,
    void* __restrict__ Cout, const float* __restrict__ bias, int M, int N, int K) {
  // LDS: A slots [4][256*32] at 0, B slots at +32768 (ushort units). 128 KiB.
  __shared__ unsigned short smem[65536];
  const int t = threadIdx.x;
  const int w = t >> 6;
  const int l = t & 63;
  const int r16 = l & 15;
  const int c4 = l >> 4;

  // bijective XCD swizzle over linear block id (m204)
  const int nx = gridDim.x;
  const int nwg = gridDim.x * gridDim.y;
  int lin = blockIdx.y * nx + blockIdx.x;
  {
    const int q = nwg >> 3, r = nwg & 7;
    const int xcd = lin & 7, idx = lin >> 3;
    lin = (xcd < r ? xcd * (q + 1) : r * (q + 1) + (xcd - r) * q) + idx;
  }
  const int m0 = (lin / nx) << 8;
  const int n0 = (lin % nx) << 8;

  // staging: thread t covers 16B chunk (row = i*128 + t>>2, slot chunk t&3),
  // global chunk pre-swizzled: c_g = (t&3) ^ ((row>>1)&3) = (t&3) ^ ((t>>3)&3)
  const int srow = t >> 2;
  const int scg = (t & 3) ^ ((t >> 3) & 3);
  const unsigned short* gA0 = A + (size_t)(m0 + srow) * K + scg * 8;
  const unsigned short* gA1 = A + (size_t)(m0 + 128 + srow) * K + scg * 8;
  const unsigned short* gB0 = B + (size_t)(n0 + srow) * K + scg * 8;
  const unsigned short* gB1 = B + (size_t)(n0 + 128 + srow) * K + scg * 8;

#define STAGE_AB(tt_)                                                         \
  {                                                                           \
    const int sa_ = ((tt_) & 3) * 8192 + w * 512;                             \
    GLOAD_LDS16(gA0 + (tt_) * 32, &smem[sa_]);                                \
    GLOAD_LDS16(gA1 + (tt_) * 32, &smem[sa_ + 4096]);                         \
    GLOAD_LDS16(gB0 + (tt_) * 32, &smem[sa_ + 32768]);                        \
    GLOAD_LDS16(gB1 + (tt_) * 32, &smem[sa_ + 36864]);                        \
  }

  // fragment read offsets (ushort units), read-side XOR swizzle matches staging
  const int swzc = (c4 ^ ((r16 >> 1) & 3)) * 8;
  const int aoff = ((w >> 2) * 128 + r16) * 32 + swzc;
  const int boff = 32768 + ((w & 3) * 64 + r16) * 32 + swzc;

  f32x4 acc[8][4] = {};
  const int NT = K >> 5;  // BK=32 sub-tiles; K=768 -> 24

#define COMPUTE_TILE(tt_)                                                     \
  {                                                                           \
    const unsigned short* pA = &smem[((tt_) & 3) * 8192 + aoff];              \
    const unsigned short* pB = &smem[((tt_) & 3) * 8192 + boff];              \
    bf16x8 af[4], ag[4], bq[4];                                               \
    _Pragma("unroll") for (int i = 0; i < 4; ++i)                             \
        af[i] = *reinterpret_cast<const bf16x8*>(pA + i * 512);               \
    _Pragma("unroll") for (int i = 0; i < 4; ++i)                             \
        bq[i] = *reinterpret_cast<const bf16x8*>(pB + i * 512);               \
    _Pragma("unroll") for (int i = 0; i < 4; ++i)                             \
        ag[i] = *reinterpret_cast<const bf16x8*>(pA + (4 + i) * 512);         \
    __builtin_amdgcn_s_setprio(1);                                            \
    _Pragma("unroll") for (int mi = 0; mi < 4; ++mi)                          \
        _Pragma("unroll") for (int ni = 0; ni < 4; ++ni)                      \
            acc[mi][ni] = __builtin_amdgcn_mfma_f32_16x16x32_bf16(            \
                af[mi], bq[ni], acc[mi][ni], 0, 0, 0);                        \
    _Pragma("unroll") for (int mi = 0; mi < 4; ++mi)                          \
        _Pragma("unroll") for (int ni = 0; ni < 4; ++ni)                      \
            acc[4 + mi][ni] = __builtin_amdgcn_mfma_f32_16x16x32_bf16(        \
                ag[mi], bq[ni], acc[4 + mi][ni], 0, 0, 0);                    \
    __builtin_amdgcn_s_setprio(0);                                            \
  }

  // prologue: stage tiles 0,1,2 (12 load-instrs); wait tile 0 (8 stay in flight)
  STAGE_AB(0) STAGE_AB(1) STAGE_AB(2)
  asm volatile("s_waitcnt vmcnt(8)" ::: "memory");
  __builtin_amdgcn_s_barrier();
  asm volatile("" ::: "memory");

  // main loop: tiles 0 .. NT-4, staging tt+3
  for (int tt = 0; tt < NT - 3; ++tt) {
    STAGE_AB(tt + 3)
    COMPUTE_TILE(tt)
    asm volatile("s_waitcnt lgkmcnt(0)" ::: "memory");  // my reads done before
    asm volatile("s_waitcnt vmcnt(8)" ::: "memory");    // tile tt+1 landed
    __builtin_amdgcn_s_barrier();
    asm volatile("" ::: "memory");
  }
  // tail tiles: NT-3, NT-2, NT-1 (no staging)
  COMPUTE_TILE(NT - 3)
  asm volatile("s_waitcnt lgkmcnt(0)" ::: "memory");
  asm volatile("s_waitcnt vmcnt(4)" ::: "memory");
  __builtin_amdgcn_s_barrier();
  asm volatile("" ::: "memory");
  COMPUTE_TILE(NT - 2)
  asm volatile("s_waitcnt lgkmcnt(0)" ::: "memory");
  asm volatile("s_waitcnt vmcnt(0)" ::: "memory");
  __builtin_amdgcn_s_barrier();
  asm volatile("" ::: "memory");
  COMPUTE_TILE(NT - 1)

  // epilogue: C/D layout col=lane&15, row=(lane>>4)*4+reg (m89/m91 verified)
  const int orow0 = m0 + (w >> 2) * 128 + c4 * 4;
  const int ocol0 = n0 + (w & 3) * 64 + r16;
#pragma unroll
  for (int mi = 0; mi < 8; ++mi) {
#pragma unroll
    for (int ni = 0; ni < 4; ++ni) {
      const int col = ocol0 + ni * 16;
      float bv = 0.0f;
      if constexpr (BIAS) bv = bias[col];
      f32x4 v = acc[mi][ni];
#pragma unroll
      for (int r = 0; r < 4; ++r) {
        const int row = orow0 + mi * 16 + r;
        float x = v[r] + bv;
        if constexpr (PHI_COLS > 0) {
          if (col < PHI_COLS) x = (x > 0.0f) ? (x + 1.0f) : __expf(x);  // elu+1
        }
        if constexpr (OUT_BF16)
          ((unsigned short*)Cout)[(size_t)row * N + col] = f2bf(x);
        else
          ((float*)Cout)[(size_t)row * N + col] = x;
      }
    }
  }
#undef STAGE_AB
#undef COMPUTE_TILE
}

// kv[m,d] = sum_n k[n,d]*v[n,m]; ksum[d] = sum_n k[n,d].  Partial over 512-n
// chunks, 8 chunks per (b,h).  Thread owns a 4x4 (m,d) tile.
__global__ __launch_bounds__(256) void kv_partial_kernel(
    const unsigned short* __restrict__ qkv, float* __restrict__ kv_part,
    float* __restrict__ ksum_part) {
  const int bh = blockIdx.x;   // 48
  const int chunk = blockIdx.y;  // 8
  const int b = bh / 12, h = bh % 12;
  const int t = threadIdx.x;
  const int tm = (t >> 4) * 4;
  const int td = (t & 15) * 4;
  const unsigned short* base = qkv + ((size_t)(b * 4096 + chunk * 512)) * 2304;
  const unsigned short* kptr = base + 768 + h * 64 + td;
  const unsigned short* vptr = base + 1536 + h * 64 + tm;
  float acc[4][4] = {};
  float ks[4] = {};
#pragma unroll 4
  for (int n = 0; n < 512; ++n) {
    const size_t off = (size_t)n * 2304;
    ushort4 ku = *reinterpret_cast<const ushort4*>(kptr + off);
    ushort4 vu = *reinterpret_cast<const ushort4*>(vptr + off);
    float kf[4] = {bf2f(ku.x), bf2f(ku.y), bf2f(ku.z), bf2f(ku.w)};
    float vf[4] = {bf2f(vu.x), bf2f(vu.y), bf2f(vu.z), bf2f(vu.w)};
#pragma unroll
    for (int i = 0; i < 4; ++i)
#pragma unroll
      for (int j = 0; j < 4; ++j) acc[i][j] += vf[i] * kf[j];
#pragma unroll
    for (int j = 0; j < 4; ++j) ks[j] += kf[j];
  }
  float* kvp = kv_part + ((size_t)(bh * 8 + chunk)) * 4096;
#pragma unroll
  for (int i = 0; i < 4; ++i)
#pragma unroll
    for (int j = 0; j < 4; ++j) kvp[(tm + i) * 64 + td + j] = acc[i][j];
  if (tm == 0) {
    float* ksp = ksum_part + (size_t)(bh * 8 + chunk) * 64;
#pragma unroll
    for (int j = 0; j < 4; ++j) ksp[td + j] = ks[j];
  }
}

__global__ __launch_bounds__(256) void kv_reduce_kernel(
    const float* __restrict__ kv_part, const float* __restrict__ ksum_part,
    float* __restrict__ kv, float* __restrict__ ksum) {
  const int bh = blockIdx.x;
  const int t = threadIdx.x;
  for (int e = t; e < 4096; e += 256) {
    float s = 0.f;
#pragma unroll
    for (int c = 0; c < 8; ++c) s += kv_part[((size_t)(bh * 8 + c)) * 4096 + e];
    kv[(size_t)bh * 4096 + e] = s;
  }
  if (t < 64) {
    float s = 0.f;
#pragma unroll
    for (int c = 0; c < 8; ++c) s += ksum_part[(size_t)(bh * 8 + c) * 64 + t];
    ksum[bh * 64 + t] = s;
  }
}

// y[n,m] = z[n] * sum_d q[n,d] kv[m,d];  z[n] = 1/(q[n,:].ksum + eps)
__global__ __launch_bounds__(256) void y_kernel(
    const unsigned short* __restrict__ qkv, const float* __restrict__ kv,
    const float* __restrict__ ksum, unsigned short* __restrict__ ybf) {
  const int bh = blockIdx.x;  // 48
  const int nc = blockIdx.y;  // 64
  const int b = bh / 12, h = bh % 12;
  const int t = threadIdx.x;
  __shared__ float qs[64][64];   // [d][n]
  __shared__ float kvs[64][64];  // [d][m]
  __shared__ float zs[64];
  const int n0 = nc * 64;
  const unsigned short* qbase = qkv + ((size_t)(b * 4096 + n0)) * 2304 + h * 64;
  {
    const int nl = t & 63, dc = t >> 6;
    const unsigned short* qrow = qbase + (size_t)nl * 2304;
    const float* kvrow = kv + (size_t)bh * 4096 + (size_t)nl * 64;
#pragma unroll
    for (int dd = 0; dd < 4; ++dd) {
      const int d0 = dc * 16 + dd * 4;
      ushort4 qu = *reinterpret_cast<const ushort4*>(qrow + d0);
      qs[d0 + 0][nl] = bf2f(qu.x);
      qs[d0 + 1][nl] = bf2f(qu.y);
      qs[d0 + 2][nl] = bf2f(qu.z);
      qs[d0 + 3][nl] = bf2f(qu.w);
      float4 kf = *reinterpret_cast<const float4*>(kvrow + d0);
      kvs[d0 + 0][nl] = kf.x;
      kvs[d0 + 1][nl] = kf.y;
      kvs[d0 + 2][nl] = kf.z;
      kvs[d0 + 3][nl] = kf.w;
    }
  }
  __syncthreads();
  if (t < 64) {
    const float* ksp = ksum + bh * 64;
    float s = 0.f;
#pragma unroll
    for (int d = 0; d < 64; ++d) s += qs[d][t] * ksp[d];
    zs[t] = 1.0f / (s + 1e-6f);
  }
  __syncthreads();
  const int tn = (t >> 4) * 4;
  const int tmm = (t & 15) * 4;
  float acc[4][4] = {};
#pragma unroll 4
  for (int d = 0; d < 64; ++d) {
    float4 qv = *reinterpret_cast<const float4*>(&qs[d][tn]);
    float4 kf = *reinterpret_cast<const float4*>(&kvs[d][tmm]);
    const float qa[4] = {qv.x, qv.y, qv.z, qv.w};
    const float ka[4] = {kf.x, kf.y, kf.z, kf.w};
#pragma unroll
    for (int i = 0; i < 4; ++i)
#pragma unroll
      for (int j = 0; j < 4; ++j) acc[i][j] += qa[i] * ka[j];
  }
  unsigned short* yrow = ybf + ((size_t)(b * 4096 + n0)) * 768 + h * 64;
#pragma unroll
  for (int i = 0; i < 4; ++i) {
    const int n = tn + i;
    const float z = zs[n];
    ushort4 o;
    o.x = f2bf(acc[i][0] * z);
    o.y = f2bf(acc[i][1] * z);
    o.z = f2bf(acc[i][2] * z);
    o.w = f2bf(acc[i][3] * z);
    *reinterpret_cast<ushort4*>(yrow + (size_t)n * 768 + tmm) = o;
  }
}

extern "C" void kernel_launch(void* const* d_in, const int* in_sizes, int n_in,
                              void* d_out, int out_size, void* d_ws, size_t ws_size,
                              hipStream_t stream) {
  const float* x = (const float*)d_in[0];
  const float* Wqkv = (const float*)d_in[1];
  const float* Wproj = (const float*)d_in[2];
  const float* bproj = (const float*)d_in[3];
  float* out = (float*)d_out;

  const int M = 16384;   // B*N tokens
  const int C = 768;
  const int N1 = 2304;   // 3C

  char* ws = (char*)d_ws;
  size_t off = 0;
  unsigned short* xb = (unsigned short*)(ws + off);  off += (size_t)M * C * 2;
  unsigned short* wqb = (unsigned short*)(ws + off); off += (size_t)N1 * C * 2;
  unsigned short* wpb = (unsigned short*)(ws + off); off += (size_t)C * C * 2;
  unsigned short* qkvb = (unsigned short*)(ws + off); off += (size_t)M * N1 * 2;
  float* kv_part = (float*)(ws + off);   off += (size_t)48 * 8 * 4096 * 4;
  float* ksum_part = (float*)(ws + off); off += (size_t)48 * 8 * 64 * 4;
  float* kv = (float*)(ws + off);        off += (size_t)48 * 4096 * 4;
  float* ksum = (float*)(ws + off);      off += (size_t)48 * 64 * 4;
  unsigned short* yb = (unsigned short*)(ws + off); off += (size_t)M * C * 2;

  cast_bf16_kernel<<<(M * C / 4 + 255) / 256, 256, 0, stream>>>(x, xb, M * C / 4);
  cast_bf16_kernel<<<(N1 * C / 4 + 255) / 256, 256, 0, stream>>>(Wqkv, wqb, N1 * C / 4);
  cast_bf16_kernel<<<(C * C / 4 + 255) / 256, 256, 0, stream>>>(Wproj, wpb, C * C / 4);

  // qkv = x @ Wqkv^T, phi fused on q,k columns (col < 1536), bf16 out
  gemm256_ring<1536, true, false>
      <<<dim3(N1 / 256, M / 256), 512, 0, stream>>>(xb, wqb, qkvb, nullptr, M, N1, C);

  kv_partial_kernel<<<dim3(48, 8), 256, 0, stream>>>(qkvb, kv_part, ksum_part);
  kv_reduce_kernel<<<48, 256, 0, stream>>>(kv_part, ksum_part, kv, ksum);
  y_kernel<<<dim3(48, 64), 256, 0, stream>>>(qkvb, kv, ksum, yb);

  // out = y @ Wproj^T + b, fp32 out
  gemm256_ring<0, false, true>
      <<<dim3(C / 256, M / 256), 512, 0, stream>>>(yb, wpb, out, bproj, M, C, C);
}

// Round 4
// 198.111 us; speedup vs baseline: 1.2025x; 1.1267x over previous
//
#include <hip/hip_runtime.h>
#include <cstdint>
#include <cstddef>

// Linear attention: B=4 N=4096 C=768 H=12 d=64
// Pipeline: cast->bf16, GEMM1 128x128 m97-style (x@Wqkv^T, fused phi),
// kv/ksum partial reduction (16 chunks), reduce, y = z*(q.kv^T),
// GEMM2 (y@Wproj^T + bias).

typedef __attribute__((ext_vector_type(8))) short bf16x8;
typedef __attribute__((ext_vector_type(4))) float f32x4;

__device__ __forceinline__ unsigned short f2bf(float f) {
  uint32_t u = __builtin_bit_cast(uint32_t, f);
  u += 0x7FFFu + ((u >> 16) & 1u);  // RNE
  return (unsigned short)(u >> 16);
}
__device__ __forceinline__ float bf2f(unsigned short h) {
  uint32_t u = ((uint32_t)h) << 16;
  return __builtin_bit_cast(float, u);
}

__global__ __launch_bounds__(256) void cast_bf16_kernel(const float* __restrict__ in,
                                                        unsigned short* __restrict__ out,
                                                        int n4) {
  int i = blockIdx.x * 256 + threadIdx.x;
  if (i >= n4) return;
  float4 v = reinterpret_cast<const float4*>(in)[i];
  ushort4 o;
  o.x = f2bf(v.x); o.y = f2bf(v.y); o.z = f2bf(v.z); o.w = f2bf(v.w);
  reinterpret_cast<ushort4*>(out)[i] = o;
}

#define GLOAD_LDS16(g, s)                                                     \
  __builtin_amdgcn_global_load_lds(                                           \
      (const __attribute__((address_space(1))) void*)(g),                     \
      (__attribute__((address_space(3))) void*)(s), 16, 0, 0)

// ============================================================================
// m97-style 128x128 tile, BK=64, 4 waves (2x2 of 64x64), 4x4 16x16x32 frags
// per wave, global_load_lds width-16, plain __syncthreads (2 per K-step).
// LDS 32 KiB -> ~4 blocks/CU co-resident; inter-block overlap hides the
// barrier drain (m114 mechanism). XOR chunk swizzle (8 chunks of 16B per
// 128B row): LDS stays linear, global source pre-swizzled, ds_read swizzled
// (rule #21). Bijective XCD blockIdx swizzle (m204).
// ============================================================================
template <int PHI_COLS, bool OUT_BF16, bool BIAS>
__global__ __launch_bounds__(256) void gemm128(
    const unsigned short* __restrict__ A, const unsigned short* __restrict__ B,
    void* __restrict__ Cout, const float* __restrict__ bias, int M, int N, int K) {
  __shared__ unsigned short As[128 * 64];
  __shared__ unsigned short Bs[128 * 64];
  const int t = threadIdx.x;
  const int w = t >> 6;
  const int l = t & 63;
  const int r16 = l & 15;
  const int c4 = l >> 4;

  // bijective XCD swizzle over linear block id (m204)
  const int nx = gridDim.x;
  const int nwg = gridDim.x * gridDim.y;
  int lin = blockIdx.y * nx + blockIdx.x;
  {
    const int q = nwg >> 3, r = nwg & 7;
    const int xcd = lin & 7, idx = lin >> 3;
    lin = (xcd < r ? xcd * (q + 1) : r * (q + 1) + (xcd - r) * q) + idx;
  }
  const int m0 = (lin / nx) * 128;
  const int n0 = (lin % nx) * 128;

  // staging: instr i covers rows i*32 + (t>>3), chunk t&7 of that row.
  // LDS linear (lane*16B); global source chunk pre-swizzled by row&7.
  const int srow = t >> 3;                      // 0..31
  const int schunk = (t & 7) ^ ((t >> 3) & 7);  // (chunk) ^ (row&7)
  const unsigned short* gA = A + (size_t)(m0 + srow) * K + schunk * 8;
  const unsigned short* gB = B + (size_t)(n0 + srow) * K + schunk * 8;
  const int lbase = w * 512;  // + i*2048; HW adds lane*8 ushorts

  const int wm = (w >> 1) * 64;
  const int wn = (w & 1) * 64;

  f32x4 acc[4][4] = {};

  for (int k0 = 0; k0 < K; k0 += 64) {
#pragma unroll
    for (int i = 0; i < 4; ++i) {
      GLOAD_LDS16(gA + k0 + (size_t)i * 32 * K, &As[lbase + i * 2048]);
      GLOAD_LDS16(gB + k0 + (size_t)i * 32 * K, &Bs[lbase + i * 2048]);
    }
    __syncthreads();
#pragma unroll
    for (int kk = 0; kk < 2; ++kk) {
      bf16x8 af[4], bfr[4];
#pragma unroll
      for (int mi = 0; mi < 4; ++mi) {
        const int R = wm + mi * 16 + r16;
        const int ch = (kk * 4 + c4) ^ (R & 7);
        af[mi] = *reinterpret_cast<const bf16x8*>(&As[R * 64 + ch * 8]);
      }
#pragma unroll
      for (int ni = 0; ni < 4; ++ni) {
        const int R = wn + ni * 16 + r16;
        const int ch = (kk * 4 + c4) ^ (R & 7);
        bfr[ni] = *reinterpret_cast<const bf16x8*>(&Bs[R * 64 + ch * 8]);
      }
#pragma unroll
      for (int mi = 0; mi < 4; ++mi)
#pragma unroll
        for (int ni = 0; ni < 4; ++ni)
          acc[mi][ni] = __builtin_amdgcn_mfma_f32_16x16x32_bf16(af[mi], bfr[ni], acc[mi][ni], 0, 0, 0);
    }
    __syncthreads();
  }

  // epilogue: C/D layout col=lane&15, row=(lane>>4)*4+reg (m89/m91 verified)
  const int rbase = c4 * 4;
#pragma unroll
  for (int mi = 0; mi < 4; ++mi) {
    const int row = m0 + wm + mi * 16 + rbase;
#pragma unroll
    for (int ni = 0; ni < 4; ++ni) {
      const int col = n0 + wn + ni * 16 + r16;
      float bv = 0.0f;
      if constexpr (BIAS) bv = bias[col];
      f32x4 v = acc[mi][ni];
#pragma unroll
      for (int r = 0; r < 4; ++r) {
        float x = v[r] + bv;
        if constexpr (PHI_COLS > 0) {
          if (col < PHI_COLS) x = (x > 0.0f) ? (x + 1.0f) : __expf(x);  // elu+1
        }
        if constexpr (OUT_BF16)
          ((unsigned short*)Cout)[(size_t)(row + r) * N + col] = f2bf(x);
        else
          ((float*)Cout)[(size_t)(row + r) * N + col] = x;
      }
    }
  }
}

// kv[m,d] = sum_n k[n,d]*v[n,m]; ksum[d] = sum_n k[n,d].  Partial over 256-n
// chunks, 16 chunks per (b,h).  Thread owns a 4x4 (m,d) tile.
__global__ __launch_bounds__(256) void kv_partial_kernel(
    const unsigned short* __restrict__ qkv, float* __restrict__ kv_part,
    float* __restrict__ ksum_part) {
  const int bh = blockIdx.x;     // 48
  const int chunk = blockIdx.y;  // 16
  const int b = bh / 12, h = bh % 12;
  const int t = threadIdx.x;
  const int tm = (t >> 4) * 4;
  const int td = (t & 15) * 4;
  const unsigned short* base = qkv + ((size_t)(b * 4096 + chunk * 256)) * 2304;
  const unsigned short* kptr = base + 768 + h * 64 + td;
  const unsigned short* vptr = base + 1536 + h * 64 + tm;
  float acc[4][4] = {};
  float ks[4] = {};
#pragma unroll 4
  for (int n = 0; n < 256; ++n) {
    const size_t off = (size_t)n * 2304;
    ushort4 ku = *reinterpret_cast<const ushort4*>(kptr + off);
    ushort4 vu = *reinterpret_cast<const ushort4*>(vptr + off);
    float kf[4] = {bf2f(ku.x), bf2f(ku.y), bf2f(ku.z), bf2f(ku.w)};
    float vf[4] = {bf2f(vu.x), bf2f(vu.y), bf2f(vu.z), bf2f(vu.w)};
#pragma unroll
    for (int i = 0; i < 4; ++i)
#pragma unroll
      for (int j = 0; j < 4; ++j) acc[i][j] += vf[i] * kf[j];
#pragma unroll
    for (int j = 0; j < 4; ++j) ks[j] += kf[j];
  }
  float* kvp = kv_part + ((size_t)(bh * 16 + chunk)) * 4096;
#pragma unroll
  for (int i = 0; i < 4; ++i)
#pragma unroll
    for (int j = 0; j < 4; ++j) kvp[(tm + i) * 64 + td + j] = acc[i][j];
  if (tm == 0) {
    float* ksp = ksum_part + (size_t)(bh * 16 + chunk) * 64;
#pragma unroll
    for (int j = 0; j < 4; ++j) ksp[td + j] = ks[j];
  }
}

__global__ __launch_bounds__(256) void kv_reduce_kernel(
    const float* __restrict__ kv_part, const float* __restrict__ ksum_part,
    float* __restrict__ kv, float* __restrict__ ksum) {
  const int bh = blockIdx.x;
  const int t = threadIdx.x;
  for (int e = t; e < 4096; e += 256) {
    float s = 0.f;
#pragma unroll
    for (int c = 0; c < 16; ++c) s += kv_part[((size_t)(bh * 16 + c)) * 4096 + e];
    kv[(size_t)bh * 4096 + e] = s;
  }
  if (t < 64) {
    float s = 0.f;
#pragma unroll
    for (int c = 0; c < 16; ++c) s += ksum_part[(size_t)(bh * 16 + c) * 64 + t];
    ksum[bh * 64 + t] = s;
  }
}

// y[n,m] = z[n] * sum_d q[n,d] kv[m,d];  z[n] = 1/(q[n,:].ksum + eps)
__global__ __launch_bounds__(256) void y_kernel(
    const unsigned short* __restrict__ qkv, const float* __restrict__ kv,
    const float* __restrict__ ksum, unsigned short* __restrict__ ybf) {
  const int bh = blockIdx.x;  // 48
  const int nc = blockIdx.y;  // 64
  const int b = bh / 12, h = bh % 12;
  const int t = threadIdx.x;
  __shared__ float qs[64][64];   // [d][n]
  __shared__ float kvs[64][64];  // [d][m]
  __shared__ float zs[64];
  const int n0 = nc * 64;
  const unsigned short* qbase = qkv + ((size_t)(b * 4096 + n0)) * 2304 + h * 64;
  {
    const int nl = t & 63, dc = t >> 6;
    const unsigned short* qrow = qbase + (size_t)nl * 2304;
    const float* kvrow = kv + (size_t)bh * 4096 + (size_t)nl * 64;
#pragma unroll
    for (int dd = 0; dd < 4; ++dd) {
      const int d0 = dc * 16 + dd * 4;
      ushort4 qu = *reinterpret_cast<const ushort4*>(qrow + d0);
      qs[d0 + 0][nl] = bf2f(qu.x);
      qs[d0 + 1][nl] = bf2f(qu.y);
      qs[d0 + 2][nl] = bf2f(qu.z);
      qs[d0 + 3][nl] = bf2f(qu.w);
      float4 kf = *reinterpret_cast<const float4*>(kvrow + d0);
      kvs[d0 + 0][nl] = kf.x;
      kvs[d0 + 1][nl] = kf.y;
      kvs[d0 + 2][nl] = kf.z;
      kvs[d0 + 3][nl] = kf.w;
    }
  }
  __syncthreads();
  if (t < 64) {
    const float* ksp = ksum + bh * 64;
    float s = 0.f;
#pragma unroll
    for (int d = 0; d < 64; ++d) s += qs[d][t] * ksp[d];
    zs[t] = 1.0f / (s + 1e-6f);
  }
  __syncthreads();
  const int tn = (t >> 4) * 4;
  const int tmm = (t & 15) * 4;
  float acc[4][4] = {};
#pragma unroll 4
  for (int d = 0; d < 64; ++d) {
    float4 qv = *reinterpret_cast<const float4*>(&qs[d][tn]);
    float4 kf = *reinterpret_cast<const float4*>(&kvs[d][tmm]);
    const float qa[4] = {qv.x, qv.y, qv.z, qv.w};
    const float ka[4] = {kf.x, kf.y, kf.z, kf.w};
#pragma unroll
    for (int i = 0; i < 4; ++i)
#pragma unroll
      for (int j = 0; j < 4; ++j) acc[i][j] += qa[i] * ka[j];
  }
  unsigned short* yrow = ybf + ((size_t)(b * 4096 + n0)) * 768 + h * 64;
#pragma unroll
  for (int i = 0; i < 4; ++i) {
    const int n = tn + i;
    const float z = zs[n];
    ushort4 o;
    o.x = f2bf(acc[i][0] * z);
    o.y = f2bf(acc[i][1] * z);
    o.z = f2bf(acc[i][2] * z);
    o.w = f2bf(acc[i][3] * z);
    *reinterpret_cast<ushort4*>(yrow + (size_t)n * 768 + tmm) = o;
  }
}

extern "C" void kernel_launch(void* const* d_in, const int* in_sizes, int n_in,
                              void* d_out, int out_size, void* d_ws, size_t ws_size,
                              hipStream_t stream) {
  const float* x = (const float*)d_in[0];
  const float* Wqkv = (const float*)d_in[1];
  const float* Wproj = (const float*)d_in[2];
  const float* bproj = (const float*)d_in[3];
  float* out = (float*)d_out;

  const int M = 16384;   // B*N tokens
  const int C = 768;
  const int N1 = 2304;   // 3C

  char* ws = (char*)d_ws;
  size_t off = 0;
  unsigned short* xb = (unsigned short*)(ws + off);  off += (size_t)M * C * 2;    // 25.2MB
  unsigned short* wqb = (unsigned short*)(ws + off); off += (size_t)N1 * C * 2;
  unsigned short* wpb = (unsigned short*)(ws + off); off += (size_t)C * C * 2;
  unsigned short* qkvb = (unsigned short*)(ws + off); off += (size_t)M * N1 * 2;
  float* kv = (float*)(ws + off);        off += (size_t)48 * 4096 * 4;
  float* ksum = (float*)(ws + off);      off += (size_t)48 * 64 * 4;
  unsigned short* yb = (unsigned short*)(ws + off); off += (size_t)M * C * 2;
  // kv_part/ksum_part overlay xb (dead after GEMM1): 12.6MB + 0.2MB < 25.2MB
  float* kv_part = (float*)xb;
  float* ksum_part = (float*)(xb + (size_t)48 * 16 * 4096 * 2);  // floats: 12.6MB in

  cast_bf16_kernel<<<(M * C / 4 + 255) / 256, 256, 0, stream>>>(x, xb, M * C / 4);
  cast_bf16_kernel<<<(N1 * C / 4 + 255) / 256, 256, 0, stream>>>(Wqkv, wqb, N1 * C / 4);
  cast_bf16_kernel<<<(C * C / 4 + 255) / 256, 256, 0, stream>>>(Wproj, wpb, C * C / 4);

  // qkv = x @ Wqkv^T, phi fused on q,k columns (col < 1536), bf16 out
  gemm128<1536, true, false>
      <<<dim3(N1 / 128, M / 128), 256, 0, stream>>>(xb, wqb, qkvb, nullptr, M, N1, C);

  kv_partial_kernel<<<dim3(48, 16), 256, 0, stream>>>(qkvb, kv_part, ksum_part);
  kv_reduce_kernel<<<48, 256, 0, stream>>>(kv_part, ksum_part, kv, ksum);
  y_kernel<<<dim3(48, 64), 256, 0, stream>>>(qkvb, kv, ksum, yb);

  // out = y @ Wproj^T + b, fp32 out
  gemm128<0, false, true>
      <<<dim3(C / 128, M / 128), 256, 0, stream>>>(yb, wpb, out, bproj, M, C, C);
}